// Round 5
// baseline (471.702 us; speedup 1.0000x reference)
//
#include <hip/hip_runtime.h>
#include <stdint.h>

// ---------------------------------------------------------------------------
// GraphSAGE(min) x3 + BatchNorm + ReLU + log_softmax, fp32, MI355X (gfx950)
//
// R1: CSR once + atomic-free segmented-min gather per layer.
// R2: parallel k_finalize.  R3: hierarchical 3-kernel scan.
// R4: (a) XCD-affine slice-partitioned CSR build: 8 edge slices, slice g
//     processed by blockIdx%8==g (one XCD under round-robin dispatch), g-major
//     csr layout -> each 400KB write region owned by one XCD L2: fixes the
//     53MB write amplification seen in k_fill (partial-line thrash across
//     non-coherent XCD L2s). Edges converted to int32 once.
//     (b) BN+ReLU fused into aggregate (per-edge, required for min under
//     general gamma sign) and into gemm/l3 rowX loads; k_bnrelu removed.
// ---------------------------------------------------------------------------

#define NS 8  // edge slices (== XCDs)

__device__ __forceinline__ float bnrelu1(float v, float mu, float is, float g, float b) {
    return fmaxf((v - mu) * is * g + b, 0.0f);
}

// ---------------------------------------------------------------------------
// zero deg8 + detect edge dtype (int64 => odd int32 slots all zero)
__global__ __launch_bounds__(256)
void k_prep(int* __restrict__ deg8, int ntot, const int* __restrict__ ei32,
            int* __restrict__ flag) {
    int i = blockIdx.x * blockDim.x + threadIdx.x;
    int stride = gridDim.x * blockDim.x;
    for (int j = i; j < ntot; j += stride) deg8[j] = 0;
    if (i == 0) {
        int allzero = 1;
        for (int t = 1; t < 32; t += 2) allzero &= (ei32[t] == 0);
        *flag = allzero;
    }
}

// ---------------------------------------------------------------------------
// edge_index -> int32 src/dst arrays (one pass)
__global__ __launch_bounds__(256)
void k_convert(const void* __restrict__ ei, int n_edges,
               const int* __restrict__ flag, int* __restrict__ src32,
               int* __restrict__ dst32) {
    const bool is64 = (*flag != 0);
    const int* e32 = (const int*)ei;
    const long long* e64 = (const long long*)ei;
    int i = blockIdx.x * blockDim.x + threadIdx.x;
    int stride = gridDim.x * blockDim.x;
    for (int e = i; e < n_edges; e += stride) {
        if (is64) { src32[e] = (int)e64[e]; dst32[e] = (int)e64[n_edges + e]; }
        else      { src32[e] = e32[e];      dst32[e] = e32[n_edges + e]; }
    }
}

// ---------------------------------------------------------------------------
// partitioned histogram: slice g handled by blocks with blockIdx%NS==g
__global__ __launch_bounds__(256)
void k_hist8(const int* __restrict__ dst32, int n_edges, int* __restrict__ deg8,
             int NN, int blocks_per_slice) {
    const int g = blockIdx.x & (NS - 1);
    const int jb = blockIdx.x >> 3;
    const int eb = (int)((long long)g * n_edges / NS);
    const int ee = (int)((long long)(g + 1) * n_edges / NS);
    const int t = threadIdx.x;
    const int stride = blocks_per_slice * 256;
    int* dg = deg8 + (size_t)g * NN;
    for (int e = eb + jb * 256 + t; e < ee; e += stride)
        atomicAdd(&dg[dst32[e]], 1);
}

// ---------------------------------------------------------------------------
// hierarchical scan over ntot = NS*NN elements
__global__ __launch_bounds__(256)
void k_scan1(const int* __restrict__ deg, int* __restrict__ bsum, int n) {
    __shared__ int red[256];
    const int t = threadIdx.x;
    const int i = blockIdx.x * 256 + t;
    red[t] = (i < n) ? deg[i] : 0;
    __syncthreads();
    for (int off = 128; off; off >>= 1) {
        if (t < off) red[t] += red[t + off];
        __syncthreads();
    }
    if (t == 0) bsum[blockIdx.x] = red[0];
}

// step 2: one block scans <=2048 block sums (2 per thread)
__global__ __launch_bounds__(1024)
void k_scan2(const int* __restrict__ bsum, int* __restrict__ boffs,
             int nb, int* __restrict__ rowptr, int ntot) {
    __shared__ int part[1024];
    const int t = threadIdx.x;
    const int i0 = 2 * t, i1 = 2 * t + 1;
    const int a = (i0 < nb) ? bsum[i0] : 0;
    const int b = (i1 < nb) ? bsum[i1] : 0;
    part[t] = a + b;
    __syncthreads();
    for (int off = 1; off < 1024; off <<= 1) {
        int v = (t >= off) ? part[t - off] : 0;
        __syncthreads();
        part[t] += v;
        __syncthreads();
    }
    const int base = (t == 0) ? 0 : part[t - 1];
    if (i0 < nb) boffs[i0] = base;
    if (i1 < nb) boffs[i1] = base + a;
    if (t == 1023) rowptr[ntot] = part[1023];
}

// step 3: per-block exclusive scan + block offset -> rowptr, cursor
__global__ __launch_bounds__(256)
void k_scan3(const int* __restrict__ deg, const int* __restrict__ boffs,
             int* __restrict__ rowptr, int* __restrict__ cursor, int n) {
    __shared__ int part[256];
    const int t = threadIdx.x;
    const int i = blockIdx.x * 256 + t;
    const int d = (i < n) ? deg[i] : 0;
    part[t] = d;
    __syncthreads();
    for (int off = 1; off < 256; off <<= 1) {
        int v = (t >= off) ? part[t - off] : 0;
        __syncthreads();
        part[t] += v;
        __syncthreads();
    }
    if (i < n) {
        int excl = boffs[blockIdx.x] + part[t] - d;
        rowptr[i] = excl;
        cursor[i] = excl;
    }
}

// ---------------------------------------------------------------------------
// partitioned fill: slice g's writes land in its contiguous csr region
__global__ __launch_bounds__(256)
void k_fill8(const int* __restrict__ src32, const int* __restrict__ dst32,
             int n_edges, int* __restrict__ cursor, int* __restrict__ csr,
             int NN, int blocks_per_slice) {
    const int g = blockIdx.x & (NS - 1);
    const int jb = blockIdx.x >> 3;
    const int eb = (int)((long long)g * n_edges / NS);
    const int ee = (int)((long long)(g + 1) * n_edges / NS);
    const int t = threadIdx.x;
    const int stride = blocks_per_slice * 256;
    int* cur = cursor + (size_t)g * NN;
    for (int e = eb + jb * 256 + t; e < ee; e += stride) {
        int d = dst32[e];
        int pos = atomicAdd(&cur[d], 1);
        csr[pos] = src32[e];
    }
}

// ---------------------------------------------------------------------------
// one wave per dst node, lane = channel; NS sub-segments per node.
// BN=true: apply bnrelu to each gathered value (monotonicity-safe fusion).
template <bool BN>
__global__ __launch_bounds__(256)
void k_agg(const float* __restrict__ x, const int* __restrict__ rowptr,
           const int* __restrict__ csr, float* __restrict__ agg, int NN,
           const float* __restrict__ mu, const float* __restrict__ istd,
           const float* __restrict__ gam, const float* __restrict__ bet) {
    const int lane = threadIdx.x & 63;
    const int wave = (blockIdx.x * blockDim.x + threadIdx.x) >> 6;
    const int nwaves = (gridDim.x * blockDim.x) >> 6;
    float s_mu = 0.f, s_is = 0.f, s_g = 0.f, s_b = 0.f;
    if (BN) { s_mu = mu[lane]; s_is = istd[lane]; s_g = gam[lane]; s_b = bet[lane]; }
    for (int n = wave; n < NN; n += nwaves) {
        int bg[NS], eg[NS];
#pragma unroll
        for (int g = 0; g < NS; ++g) {
            bg[g] = rowptr[g * NN + n];
            eg[g] = rowptr[g * NN + n + 1];
        }
        float m = __builtin_inff();
        int cnt = 0;
#pragma unroll
        for (int g = 0; g < NS; ++g) {
            int e = bg[g];
            const int end = eg[g];
            cnt += end - e;
            for (; e + 4 <= end; e += 4) {
                int s0 = csr[e], s1 = csr[e + 1], s2 = csr[e + 2], s3 = csr[e + 3];
                float v0 = x[(size_t)s0 * 64 + lane];
                float v1 = x[(size_t)s1 * 64 + lane];
                float v2 = x[(size_t)s2 * 64 + lane];
                float v3 = x[(size_t)s3 * 64 + lane];
                if (BN) {
                    v0 = bnrelu1(v0, s_mu, s_is, s_g, s_b);
                    v1 = bnrelu1(v1, s_mu, s_is, s_g, s_b);
                    v2 = bnrelu1(v2, s_mu, s_is, s_g, s_b);
                    v3 = bnrelu1(v3, s_mu, s_is, s_g, s_b);
                }
                m = fminf(m, fminf(fminf(v0, v1), fminf(v2, v3)));
            }
            for (; e < end; ++e) {
                float v = x[(size_t)csr[e] * 64 + lane];
                if (BN) v = bnrelu1(v, s_mu, s_is, s_g, s_b);
                m = fminf(m, v);
            }
        }
        agg[(size_t)n * 64 + lane] = (cnt > 0) ? m : 0.0f;
    }
}

// ---------------------------------------------------------------------------
// 64->64 GEMM; BNX=true applies bnrelu to the xin (lin_r) operand inline.
template <bool BNX>
__global__ __launch_bounds__(256)
void k_gemm64(const float* __restrict__ agg, const float* __restrict__ xin,
              const float* __restrict__ Wl, const float* __restrict__ bl,
              const float* __restrict__ Wr, float* __restrict__ hout,
              double* __restrict__ psum, double* __restrict__ psq, int n_nodes,
              const float* __restrict__ mu, const float* __restrict__ istd,
              const float* __restrict__ gam, const float* __restrict__ bet) {
    __shared__ float sWl[64][64];
    __shared__ float sWr[64][64];
    __shared__ float rowA[4][64];
    __shared__ float rowX[4][64];
    __shared__ double red[4][64];
    const int t = threadIdx.x, c = t & 63, ln = t >> 6;
    for (int i = t; i < 4096; i += 256) {
        ((float*)sWl)[i] = Wl[i];
        ((float*)sWr)[i] = Wr[i];
    }
    float s_mu = 0.f, s_is = 0.f, s_g = 0.f, s_b = 0.f;
    if (BNX) { s_mu = mu[c]; s_is = istd[c]; s_g = gam[c]; s_b = bet[c]; }
    const float bc = bl[c];
    double lsum = 0.0, lsq = 0.0;
    const int nchunk = (n_nodes + 3) >> 2;
    for (int chunk = blockIdx.x; chunk < nchunk; chunk += gridDim.x) {
        const int node = chunk * 4 + ln;
        __syncthreads();
        if (node < n_nodes) {
            rowA[ln][c] = agg[(size_t)node * 64 + c];
            float v = xin[(size_t)node * 64 + c];
            if (BNX) v = bnrelu1(v, s_mu, s_is, s_g, s_b);
            rowX[ln][c] = v;
        }
        __syncthreads();
        if (node < n_nodes) {
            float acc = bc;
#pragma unroll
            for (int k = 0; k < 64; ++k)
                acc = fmaf(rowA[ln][k], sWl[k][c], fmaf(rowX[ln][k], sWr[k][c], acc));
            hout[(size_t)node * 64 + c] = acc;
            lsum += (double)acc;
            lsq  += (double)acc * (double)acc;
        }
    }
    __syncthreads();
    red[ln][c] = lsum;
    __syncthreads();
    if (ln == 0)
        psum[(size_t)blockIdx.x * 64 + c] = red[0][c] + red[1][c] + red[2][c] + red[3][c];
    __syncthreads();
    red[ln][c] = lsq;
    __syncthreads();
    if (ln == 0)
        psq[(size_t)blockIdx.x * 64 + c] = red[0][c] + red[1][c] + red[2][c] + red[3][c];
}

// ---------------------------------------------------------------------------
__global__ __launch_bounds__(1024)
void k_finalize(const double* __restrict__ psum, const double* __restrict__ psq,
                float* __restrict__ mu, float* __restrict__ istd,
                int n_nodes, int nblocks) {
    __shared__ double s_s[16][64];
    __shared__ double s_q[16][64];
    const int t = threadIdx.x;
    const int c = t & 63, g = t >> 6;
    double s = 0.0, q = 0.0;
    for (int b = g; b < nblocks; b += 16) {
        s += psum[(size_t)b * 64 + c];
        q += psq[(size_t)b * 64 + c];
    }
    s_s[g][c] = s;
    s_q[g][c] = q;
    __syncthreads();
    if (g == 0) {
        double S = 0.0, Q = 0.0;
#pragma unroll
        for (int i = 0; i < 16; ++i) { S += s_s[i][c]; Q += s_q[i][c]; }
        double m = S / n_nodes;
        double var = Q / n_nodes - m * m;
        mu[c] = (float)m;
        istd[c] = (float)(1.0 / sqrt(var + 1e-5));
    }
}

// ---------------------------------------------------------------------------
// 64->16 GEMM + log_softmax; bnrelu applied to xin operand inline.
__global__ __launch_bounds__(256)
void k_l3(const float* __restrict__ agg, const float* __restrict__ xin,
          const float* __restrict__ W3l, const float* __restrict__ b3,
          const float* __restrict__ W3r, float* __restrict__ out, int n_nodes,
          const float* __restrict__ mu, const float* __restrict__ istd,
          const float* __restrict__ gam, const float* __restrict__ bet) {
    __shared__ float sWl[64][16];
    __shared__ float sWr[64][16];
    __shared__ float rowA[16][65];
    __shared__ float rowX[16][65];
    const int t = threadIdx.x;
    for (int i = t; i < 1024; i += 256) {
        ((float*)sWl)[i] = W3l[i];
        ((float*)sWr)[i] = W3r[i];
    }
    const int kc = t & 63;  // channel handled by this loader thread (const: 256%64==0)
    const float s_mu = mu[kc], s_is = istd[kc], s_g = gam[kc], s_b = bet[kc];
    const int base = blockIdx.x * 16;
#pragma unroll
    for (int i = 0; i < 4; ++i) {
        int j = t + i * 256;
        int nd = j >> 6, k = j & 63;
        int gnode = base + nd;
        if (gnode < n_nodes) {
            rowA[nd][k] = agg[(size_t)gnode * 64 + k];
            rowX[nd][k] = bnrelu1(xin[(size_t)gnode * 64 + k], s_mu, s_is, s_g, s_b);
        } else {
            rowA[nd][k] = 0.0f;
            rowX[nd][k] = 0.0f;
        }
    }
    __syncthreads();
    const int n = t >> 4, c = t & 15;
    float acc = b3[c];
#pragma unroll
    for (int k = 0; k < 64; ++k)
        acc = fmaf(rowA[n][k], sWl[k][c], fmaf(rowX[n][k], sWr[k][c], acc));
    float m = acc;
    for (int off = 8; off; off >>= 1) m = fmaxf(m, __shfl_xor(m, off, 16));
    float ex = expf(acc - m);
    float ssum = ex;
    for (int off = 8; off; off >>= 1) ssum += __shfl_xor(ssum, off, 16);
    if (base + n < n_nodes)
        out[(size_t)(base + n) * 16 + c] = (acc - m) - logf(ssum);
}

// ---------------------------------------------------------------------------
extern "C" void kernel_launch(void* const* d_in, const int* in_sizes, int n_in,
                              void* d_out, int out_size, void* d_ws, size_t ws_size,
                              hipStream_t stream) {
    (void)n_in; (void)out_size; (void)ws_size;
    const float* x   = (const float*)d_in[0];
    const void*  ei  = d_in[1];
    const float* W1l = (const float*)d_in[2];
    const float* b1  = (const float*)d_in[3];
    const float* W1r = (const float*)d_in[4];
    const float* g1  = (const float*)d_in[5];
    const float* be1 = (const float*)d_in[6];
    const float* W2l = (const float*)d_in[7];
    const float* b2  = (const float*)d_in[8];
    const float* W2r = (const float*)d_in[9];
    const float* g2  = (const float*)d_in[10];
    const float* be2 = (const float*)d_in[11];
    const float* W3l = (const float*)d_in[12];
    const float* b3  = (const float*)d_in[13];
    const float* W3r = (const float*)d_in[14];
    float* out = (float*)d_out;

    const int NN = in_sizes[0] / 64;
    const int n_edges = in_sizes[1] / 2;
    const int nAgg = NN * 64;
    const int ntot = NS * NN;

    size_t off = 0;
    auto alloc = [&](size_t bytes) {
        void* p = (char*)d_ws + off;
        off = (off + bytes + 255) & ~(size_t)255;
        return p;
    };
    float* agg    = (float*)alloc((size_t)nAgg * 4);
    float* hA     = (float*)alloc((size_t)nAgg * 4);
    float* hB     = (float*)alloc((size_t)nAgg * 4);
    int*   csr    = (int*)  alloc((size_t)n_edges * 4);
    int*   src32  = (int*)  alloc((size_t)n_edges * 4);
    int*   dst32  = (int*)  alloc((size_t)n_edges * 4);
    int*   rowptr = (int*)  alloc((size_t)(ntot + 1) * 4);
    int*   cursor = (int*)  alloc((size_t)ntot * 4);
    int*   deg8   = (int*)  alloc((size_t)ntot * 4);
    int*   bsum   = (int*)  alloc(2048 * 4);
    int*   boffs  = (int*)  alloc(2048 * 4);
    const int GG = 512;
    double* psum  = (double*)alloc((size_t)GG * 64 * 8);
    double* psq   = (double*)alloc((size_t)GG * 64 * 8);
    float*  mu1   = (float*) alloc(64 * 4);
    float*  istd1 = (float*) alloc(64 * 4);
    float*  mu2   = (float*) alloc(64 * 4);
    float*  istd2 = (float*) alloc(64 * 4);
    int*    flag  = (int*)   alloc(4);

    const int GHF = 1024;                 // hist/fill grid (128 blocks/slice)
    const int BPS = GHF / NS;
    const int NB2 = (ntot + 255) / 256;   // 1563 for 50k nodes -> fits scan2
    const int GA = 2048;
    const int GL3 = (NN + 15) / 16;

    // ---- build partitioned CSR once ----
    k_prep   <<<256, 256, 0, stream>>>(deg8, ntot, (const int*)ei, flag);
    k_convert<<<1024, 256, 0, stream>>>(ei, n_edges, flag, src32, dst32);
    k_hist8  <<<GHF, 256, 0, stream>>>(dst32, n_edges, deg8, NN, BPS);
    k_scan1  <<<NB2, 256, 0, stream>>>(deg8, bsum, ntot);
    k_scan2  <<<1, 1024, 0, stream>>>(bsum, boffs, NB2, rowptr, ntot);
    k_scan3  <<<NB2, 256, 0, stream>>>(deg8, boffs, rowptr, cursor, ntot);
    k_fill8  <<<GHF, 256, 0, stream>>>(src32, dst32, n_edges, cursor, csr, NN, BPS);

    // ---- layer 1 ----
    k_agg<false><<<GA, 256, 0, stream>>>(x, rowptr, csr, agg, NN,
                                         nullptr, nullptr, nullptr, nullptr);
    k_gemm64<false><<<GG, 256, 0, stream>>>(agg, x, W1l, b1, W1r, hA, psum, psq, NN,
                                            nullptr, nullptr, nullptr, nullptr);
    k_finalize<<<1, 1024, 0, stream>>>(psum, psq, mu1, istd1, NN, GG);
    // ---- layer 2 (BN of layer 1 fused into consumers) ----
    k_agg<true><<<GA, 256, 0, stream>>>(hA, rowptr, csr, agg, NN, mu1, istd1, g1, be1);
    k_gemm64<true><<<GG, 256, 0, stream>>>(agg, hA, W2l, b2, W2r, hB, psum, psq, NN,
                                           mu1, istd1, g1, be1);
    k_finalize<<<1, 1024, 0, stream>>>(psum, psq, mu2, istd2, NN, GG);
    // ---- layer 3 (BN of layer 2 fused into consumers) ----
    k_agg<true><<<GA, 256, 0, stream>>>(hB, rowptr, csr, agg, NN, mu2, istd2, g2, be2);
    k_l3<<<GL3, 256, 0, stream>>>(agg, hB, W3l, b3, W3r, out, NN, mu2, istd2, g2, be2);
}

// Round 6
// 404.649 us; speedup vs baseline: 1.1657x; 1.1657x over previous
//
#include <hip/hip_runtime.h>
#include <stdint.h>

// ---------------------------------------------------------------------------
// GraphSAGE(min) x3 + BatchNorm + ReLU + log_softmax, fp32, MI355X (gfx950)
//
// R1: CSR once + atomic-free segmented-min gather per layer.
// R2: parallel k_finalize.  R3: hierarchical 3-kernel scan.
// R4 post-mortem: edge-slice CSR fixed fill thrash but broke the aggregate
//     (8 sub-segments of avg degree 2 -> no gather ILP). 
// R5: single dst-major CSR (aggregate back to 1 segment/node, 4-wide unroll,
//     BN fused) + dst-RANGE-partitioned hist/fill: XCD group g=blockIdx%8
//     scans all edges, commits only dst in its node range -> csr/cursor
//     writes XCD-local (kills the 53MB partial-line writeback thrash), CSR
//     layout unchanged for the consumer.
// ---------------------------------------------------------------------------

#define NG 8  // dst-range groups (== XCDs, blockIdx%8 round-robin heuristic)

__device__ __forceinline__ float bnrelu1(float v, float mu, float is, float g, float b) {
    return fmaxf((v - mu) * is * g + b, 0.0f);
}

// ---------------------------------------------------------------------------
// zero deg + detect edge dtype (int64 => odd int32 slots all zero)
__global__ __launch_bounds__(256)
void k_prep(int* __restrict__ deg, int n_nodes, const int* __restrict__ ei32,
            int* __restrict__ flag) {
    int i = blockIdx.x * blockDim.x + threadIdx.x;
    int stride = gridDim.x * blockDim.x;
    for (int j = i; j < n_nodes; j += stride) deg[j] = 0;
    if (i == 0) {
        int allzero = 1;
        for (int t = 1; t < 32; t += 2) allzero &= (ei32[t] == 0);
        *flag = allzero;
    }
}

// ---------------------------------------------------------------------------
// edge_index -> int32 src/dst arrays (one pass)
__global__ __launch_bounds__(256)
void k_convert(const void* __restrict__ ei, int n_edges,
               const int* __restrict__ flag, int* __restrict__ src32,
               int* __restrict__ dst32) {
    const bool is64 = (*flag != 0);
    const int* e32 = (const int*)ei;
    const long long* e64 = (const long long*)ei;
    int i = blockIdx.x * blockDim.x + threadIdx.x;
    int stride = gridDim.x * blockDim.x;
    for (int e = i; e < n_edges; e += stride) {
        if (is64) { src32[e] = (int)e64[e]; dst32[e] = (int)e64[n_edges + e]; }
        else      { src32[e] = e32[e];      dst32[e] = e32[n_edges + e]; }
    }
}

// ---------------------------------------------------------------------------
// dst-range-partitioned histogram: group g commits only its node range.
__global__ __launch_bounds__(256)
void k_hist_r(const int* __restrict__ dst32, int n_edges, int* __restrict__ deg,
              int NN, int blocks_per_group) {
    const int g = blockIdx.x & (NG - 1);
    const int jb = blockIdx.x >> 3;
    const int lo = (int)((long long)g * NN / NG);
    const int hi = (int)((long long)(g + 1) * NN / NG);
    const int stride = blocks_per_group * 256;
    for (int e = jb * 256 + threadIdx.x; e < n_edges; e += stride) {
        int d = dst32[e];
        if (d >= lo && d < hi) atomicAdd(&deg[d], 1);
    }
}

// ---------------------------------------------------------------------------
// hierarchical scan
__global__ __launch_bounds__(256)
void k_scan1(const int* __restrict__ deg, int* __restrict__ bsum, int n) {
    __shared__ int red[256];
    const int t = threadIdx.x;
    const int i = blockIdx.x * 256 + t;
    red[t] = (i < n) ? deg[i] : 0;
    __syncthreads();
    for (int off = 128; off; off >>= 1) {
        if (t < off) red[t] += red[t + off];
        __syncthreads();
    }
    if (t == 0) bsum[blockIdx.x] = red[0];
}

__global__ __launch_bounds__(1024)
void k_scan2(const int* __restrict__ bsum, int* __restrict__ boffs,
             int nb, int* __restrict__ rowptr, int n) {
    __shared__ int part[1024];
    const int t = threadIdx.x;
    part[t] = (t < nb) ? bsum[t] : 0;
    __syncthreads();
    for (int off = 1; off < 1024; off <<= 1) {
        int v = (t >= off) ? part[t - off] : 0;
        __syncthreads();
        part[t] += v;
        __syncthreads();
    }
    if (t < nb) boffs[t] = (t == 0) ? 0 : part[t - 1];
    if (t == 0) rowptr[n] = part[nb - 1];
}

__global__ __launch_bounds__(256)
void k_scan3(const int* __restrict__ deg, const int* __restrict__ boffs,
             int* __restrict__ rowptr, int* __restrict__ cursor, int n) {
    __shared__ int part[256];
    const int t = threadIdx.x;
    const int i = blockIdx.x * 256 + t;
    const int d = (i < n) ? deg[i] : 0;
    part[t] = d;
    __syncthreads();
    for (int off = 1; off < 256; off <<= 1) {
        int v = (t >= off) ? part[t - off] : 0;
        __syncthreads();
        part[t] += v;
        __syncthreads();
    }
    if (i < n) {
        int excl = boffs[blockIdx.x] + part[t] - d;
        rowptr[i] = excl;
        cursor[i] = excl;
    }
}

// ---------------------------------------------------------------------------
// dst-range-partitioned fill: group g's csr writes land in one contiguous
// XCD-local region; CSR layout stays dst-major for the aggregate.
__global__ __launch_bounds__(256)
void k_fill_r(const int* __restrict__ src32, const int* __restrict__ dst32,
              int n_edges, int* __restrict__ cursor, int* __restrict__ csr,
              int NN, int blocks_per_group) {
    const int g = blockIdx.x & (NG - 1);
    const int jb = blockIdx.x >> 3;
    const int lo = (int)((long long)g * NN / NG);
    const int hi = (int)((long long)(g + 1) * NN / NG);
    const int stride = blocks_per_group * 256;
    for (int e = jb * 256 + threadIdx.x; e < n_edges; e += stride) {
        int d = dst32[e];
        if (d >= lo && d < hi) {
            int pos = atomicAdd(&cursor[d], 1);
            csr[pos] = src32[e];
        }
    }
}

// ---------------------------------------------------------------------------
// one wave per dst node, lane = channel; single segment, 4 gathers in flight.
// BN=true applies bnrelu to each gathered value (monotonic -> safe fusion).
template <bool BN>
__global__ __launch_bounds__(256)
void k_agg(const float* __restrict__ x, const int* __restrict__ rowptr,
           const int* __restrict__ csr, float* __restrict__ agg, int NN,
           const float* __restrict__ mu, const float* __restrict__ istd,
           const float* __restrict__ gam, const float* __restrict__ bet) {
    const int lane = threadIdx.x & 63;
    const int wave = (blockIdx.x * blockDim.x + threadIdx.x) >> 6;
    const int nwaves = (gridDim.x * blockDim.x) >> 6;
    float s_mu = 0.f, s_is = 0.f, s_g = 0.f, s_b = 0.f;
    if (BN) { s_mu = mu[lane]; s_is = istd[lane]; s_g = gam[lane]; s_b = bet[lane]; }
    for (int n = wave; n < NN; n += nwaves) {
        const int beg = rowptr[n], end = rowptr[n + 1];
        float m = __builtin_inff();
        int e = beg;
        for (; e + 4 <= end; e += 4) {
            int s0 = csr[e], s1 = csr[e + 1], s2 = csr[e + 2], s3 = csr[e + 3];
            float v0 = x[(size_t)s0 * 64 + lane];
            float v1 = x[(size_t)s1 * 64 + lane];
            float v2 = x[(size_t)s2 * 64 + lane];
            float v3 = x[(size_t)s3 * 64 + lane];
            if (BN) {
                v0 = bnrelu1(v0, s_mu, s_is, s_g, s_b);
                v1 = bnrelu1(v1, s_mu, s_is, s_g, s_b);
                v2 = bnrelu1(v2, s_mu, s_is, s_g, s_b);
                v3 = bnrelu1(v3, s_mu, s_is, s_g, s_b);
            }
            m = fminf(m, fminf(fminf(v0, v1), fminf(v2, v3)));
        }
        for (; e < end; ++e) {
            float v = x[(size_t)csr[e] * 64 + lane];
            if (BN) v = bnrelu1(v, s_mu, s_is, s_g, s_b);
            m = fminf(m, v);
        }
        agg[(size_t)n * 64 + lane] = (end > beg) ? m : 0.0f;
    }
}

// ---------------------------------------------------------------------------
// 64->64 GEMM; BNX=true applies bnrelu to the xin (lin_r) operand inline.
template <bool BNX>
__global__ __launch_bounds__(256)
void k_gemm64(const float* __restrict__ agg, const float* __restrict__ xin,
              const float* __restrict__ Wl, const float* __restrict__ bl,
              const float* __restrict__ Wr, float* __restrict__ hout,
              double* __restrict__ psum, double* __restrict__ psq, int n_nodes,
              const float* __restrict__ mu, const float* __restrict__ istd,
              const float* __restrict__ gam, const float* __restrict__ bet) {
    __shared__ float sWl[64][64];
    __shared__ float sWr[64][64];
    __shared__ float rowA[4][64];
    __shared__ float rowX[4][64];
    __shared__ double red[4][64];
    const int t = threadIdx.x, c = t & 63, ln = t >> 6;
    for (int i = t; i < 4096; i += 256) {
        ((float*)sWl)[i] = Wl[i];
        ((float*)sWr)[i] = Wr[i];
    }
    float s_mu = 0.f, s_is = 0.f, s_g = 0.f, s_b = 0.f;
    if (BNX) { s_mu = mu[c]; s_is = istd[c]; s_g = gam[c]; s_b = bet[c]; }
    const float bc = bl[c];
    double lsum = 0.0, lsq = 0.0;
    const int nchunk = (n_nodes + 3) >> 2;
    for (int chunk = blockIdx.x; chunk < nchunk; chunk += gridDim.x) {
        const int node = chunk * 4 + ln;
        __syncthreads();
        if (node < n_nodes) {
            rowA[ln][c] = agg[(size_t)node * 64 + c];
            float v = xin[(size_t)node * 64 + c];
            if (BNX) v = bnrelu1(v, s_mu, s_is, s_g, s_b);
            rowX[ln][c] = v;
        }
        __syncthreads();
        if (node < n_nodes) {
            float acc = bc;
#pragma unroll
            for (int k = 0; k < 64; ++k)
                acc = fmaf(rowA[ln][k], sWl[k][c], fmaf(rowX[ln][k], sWr[k][c], acc));
            hout[(size_t)node * 64 + c] = acc;
            lsum += (double)acc;
            lsq  += (double)acc * (double)acc;
        }
    }
    __syncthreads();
    red[ln][c] = lsum;
    __syncthreads();
    if (ln == 0)
        psum[(size_t)blockIdx.x * 64 + c] = red[0][c] + red[1][c] + red[2][c] + red[3][c];
    __syncthreads();
    red[ln][c] = lsq;
    __syncthreads();
    if (ln == 0)
        psq[(size_t)blockIdx.x * 64 + c] = red[0][c] + red[1][c] + red[2][c] + red[3][c];
}

// ---------------------------------------------------------------------------
__global__ __launch_bounds__(1024)
void k_finalize(const double* __restrict__ psum, const double* __restrict__ psq,
                float* __restrict__ mu, float* __restrict__ istd,
                int n_nodes, int nblocks) {
    __shared__ double s_s[16][64];
    __shared__ double s_q[16][64];
    const int t = threadIdx.x;
    const int c = t & 63, g = t >> 6;
    double s = 0.0, q = 0.0;
    for (int b = g; b < nblocks; b += 16) {
        s += psum[(size_t)b * 64 + c];
        q += psq[(size_t)b * 64 + c];
    }
    s_s[g][c] = s;
    s_q[g][c] = q;
    __syncthreads();
    if (g == 0) {
        double S = 0.0, Q = 0.0;
#pragma unroll
        for (int i = 0; i < 16; ++i) { S += s_s[i][c]; Q += s_q[i][c]; }
        double m = S / n_nodes;
        double var = Q / n_nodes - m * m;
        mu[c] = (float)m;
        istd[c] = (float)(1.0 / sqrt(var + 1e-5));
    }
}

// ---------------------------------------------------------------------------
// 64->16 GEMM + log_softmax; bnrelu applied to xin operand inline.
__global__ __launch_bounds__(256)
void k_l3(const float* __restrict__ agg, const float* __restrict__ xin,
          const float* __restrict__ W3l, const float* __restrict__ b3,
          const float* __restrict__ W3r, float* __restrict__ out, int n_nodes,
          const float* __restrict__ mu, const float* __restrict__ istd,
          const float* __restrict__ gam, const float* __restrict__ bet) {
    __shared__ float sWl[64][16];
    __shared__ float sWr[64][16];
    __shared__ float rowA[16][65];
    __shared__ float rowX[16][65];
    const int t = threadIdx.x;
    for (int i = t; i < 1024; i += 256) {
        ((float*)sWl)[i] = W3l[i];
        ((float*)sWr)[i] = W3r[i];
    }
    const int kc = t & 63;
    const float s_mu = mu[kc], s_is = istd[kc], s_g = gam[kc], s_b = bet[kc];
    const int base = blockIdx.x * 16;
#pragma unroll
    for (int i = 0; i < 4; ++i) {
        int j = t + i * 256;
        int nd = j >> 6, k = j & 63;
        int gnode = base + nd;
        if (gnode < n_nodes) {
            rowA[nd][k] = agg[(size_t)gnode * 64 + k];
            rowX[nd][k] = bnrelu1(xin[(size_t)gnode * 64 + k], s_mu, s_is, s_g, s_b);
        } else {
            rowA[nd][k] = 0.0f;
            rowX[nd][k] = 0.0f;
        }
    }
    __syncthreads();
    const int n = t >> 4, c = t & 15;
    float acc = b3[c];
#pragma unroll
    for (int k = 0; k < 64; ++k)
        acc = fmaf(rowA[n][k], sWl[k][c], fmaf(rowX[n][k], sWr[k][c], acc));
    float m = acc;
    for (int off = 8; off; off >>= 1) m = fmaxf(m, __shfl_xor(m, off, 16));
    float ex = expf(acc - m);
    float ssum = ex;
    for (int off = 8; off; off >>= 1) ssum += __shfl_xor(ssum, off, 16);
    if (base + n < n_nodes)
        out[(size_t)(base + n) * 16 + c] = (acc - m) - logf(ssum);
}

// ---------------------------------------------------------------------------
extern "C" void kernel_launch(void* const* d_in, const int* in_sizes, int n_in,
                              void* d_out, int out_size, void* d_ws, size_t ws_size,
                              hipStream_t stream) {
    (void)n_in; (void)out_size; (void)ws_size;
    const float* x   = (const float*)d_in[0];
    const void*  ei  = d_in[1];
    const float* W1l = (const float*)d_in[2];
    const float* b1  = (const float*)d_in[3];
    const float* W1r = (const float*)d_in[4];
    const float* g1  = (const float*)d_in[5];
    const float* be1 = (const float*)d_in[6];
    const float* W2l = (const float*)d_in[7];
    const float* b2  = (const float*)d_in[8];
    const float* W2r = (const float*)d_in[9];
    const float* g2  = (const float*)d_in[10];
    const float* be2 = (const float*)d_in[11];
    const float* W3l = (const float*)d_in[12];
    const float* b3  = (const float*)d_in[13];
    const float* W3r = (const float*)d_in[14];
    float* out = (float*)d_out;

    const int NN = in_sizes[0] / 64;
    const int n_edges = in_sizes[1] / 2;
    const int nAgg = NN * 64;

    size_t off = 0;
    auto alloc = [&](size_t bytes) {
        void* p = (char*)d_ws + off;
        off = (off + bytes + 255) & ~(size_t)255;
        return p;
    };
    float* agg    = (float*)alloc((size_t)nAgg * 4);
    float* hA     = (float*)alloc((size_t)nAgg * 4);
    float* hB     = (float*)alloc((size_t)nAgg * 4);
    int*   csr    = (int*)  alloc((size_t)n_edges * 4);
    int*   src32  = (int*)  alloc((size_t)n_edges * 4);
    int*   dst32  = (int*)  alloc((size_t)n_edges * 4);
    int*   rowptr = (int*)  alloc((size_t)(NN + 1) * 4);
    int*   cursor = (int*)  alloc((size_t)NN * 4);
    int*   deg    = (int*)  alloc((size_t)NN * 4);
    int*   bsum   = (int*)  alloc(1024 * 4);
    int*   boffs  = (int*)  alloc(1024 * 4);
    const int GG = 512;
    double* psum  = (double*)alloc((size_t)GG * 64 * 8);
    double* psq   = (double*)alloc((size_t)GG * 64 * 8);
    float*  mu1   = (float*) alloc(64 * 4);
    float*  istd1 = (float*) alloc(64 * 4);
    float*  mu2   = (float*) alloc(64 * 4);
    float*  istd2 = (float*) alloc(64 * 4);
    int*    flag  = (int*)   alloc(4);

    const int GHF = 1024;               // 8 groups x 128 blocks
    const int BPG = GHF / NG;
    const int NB = (NN + 255) / 256;    // 196 <= 1024
    const int GA = 2048;
    const int GL3 = (NN + 15) / 16;

    // ---- build CSR once (dst-major; build partitioned by dst-range) ----
    k_prep   <<<256, 256, 0, stream>>>(deg, NN, (const int*)ei, flag);
    k_convert<<<1024, 256, 0, stream>>>(ei, n_edges, flag, src32, dst32);
    k_hist_r <<<GHF, 256, 0, stream>>>(dst32, n_edges, deg, NN, BPG);
    k_scan1  <<<NB, 256, 0, stream>>>(deg, bsum, NN);
    k_scan2  <<<1, 1024, 0, stream>>>(bsum, boffs, NB, rowptr, NN);
    k_scan3  <<<NB, 256, 0, stream>>>(deg, boffs, rowptr, cursor, NN);
    k_fill_r <<<GHF, 256, 0, stream>>>(src32, dst32, n_edges, cursor, csr, NN, BPG);

    // ---- layer 1 ----
    k_agg<false><<<GA, 256, 0, stream>>>(x, rowptr, csr, agg, NN,
                                         nullptr, nullptr, nullptr, nullptr);
    k_gemm64<false><<<GG, 256, 0, stream>>>(agg, x, W1l, b1, W1r, hA, psum, psq, NN,
                                            nullptr, nullptr, nullptr, nullptr);
    k_finalize<<<1, 1024, 0, stream>>>(psum, psq, mu1, istd1, NN, GG);
    // ---- layer 2 (BN of layer 1 fused into consumers) ----
    k_agg<true><<<GA, 256, 0, stream>>>(hA, rowptr, csr, agg, NN, mu1, istd1, g1, be1);
    k_gemm64<true><<<GG, 256, 0, stream>>>(agg, hA, W2l, b2, W2r, hB, psum, psq, NN,
                                           mu1, istd1, g1, be1);
    k_finalize<<<1, 1024, 0, stream>>>(psum, psq, mu2, istd2, NN, GG);
    // ---- layer 3 (BN of layer 2 fused into consumers) ----
    k_agg<true><<<GA, 256, 0, stream>>>(hB, rowptr, csr, agg, NN, mu2, istd2, g2, be2);
    k_l3<<<GL3, 256, 0, stream>>>(agg, hB, W3l, b3, W3r, out, NN, mu2, istd2, g2, be2);
}